// Round 1
// 90.599 us; speedup vs baseline: 1.0210x; 1.0210x over previous
//
#include <hip/hip_runtime.h>

#define BSZ 256
#define DIM 1024

typedef __attribute__((ext_vector_type(8))) short short8;   // 8 x bf16 bits (4 VGPR)
typedef __attribute__((ext_vector_type(4))) float f32x4;

__device__ __forceinline__ unsigned pack_bf16x2(float f0, float f1) {
    union { float f; unsigned u; } c0, c1;
    c0.f = f0; c1.f = f1;
    return ((c0.u + 0x8000u) >> 16) | ((c1.u + 0x8000u) & 0xFFFF0000u);
}

#if __has_builtin(__builtin_amdgcn_exp2f)
#define EXP2F(x) __builtin_amdgcn_exp2f(x)
#else
#define EXP2F(x) exp2f(x)
#endif

// ---------------------------------------------------------------------------
// Kernel 1: fused QKV projection, K-split x2 (unchanged from R7/R8).
// qkv[z][widx][m][n] = sum_{k in half z} x[m][k]*W[n][k] (+bias if z==0)
// Tile 32x64, BK=64, 8 iters, double-buffered LDS + register prefetch,
// one barrier per iter. Grid (48, 8, 2) = 768 blocks -> 3 blocks/CU.
// ---------------------------------------------------------------------------
__global__ __launch_bounds__(256) void qkv_gemm(
    const float* __restrict__ x,
    const float* __restrict__ Wq, const float* __restrict__ bq,
    const float* __restrict__ Wk, const float* __restrict__ bk,
    const float* __restrict__ Wv, const float* __restrict__ bv,
    float* __restrict__ qkv)
{
    __shared__ __align__(16) ushort As[2][32 * 72];
    __shared__ __align__(16) ushort Bs[2][64 * 72];

    const int tid  = threadIdx.x;
    const int lane = tid & 63;
    const int wave = tid >> 6;
    const int wm = wave >> 1, wn = wave & 1;
    const int l15 = lane & 15, quad = lane >> 4;

    const int widx = blockIdx.x >> 4;             // 0=q 1=k 2=v
    const int n0   = (blockIdx.x & 15) * 64;
    const int m0   = blockIdx.y * 32;
    const int koff = blockIdx.z * 512;            // K-half

    const float* W    = (widx == 0) ? Wq : (widx == 1) ? Wk : Wv;
    const float* bias = (widx == 0) ? bq : (widx == 1) ? bk : bv;
    float* out = qkv + (size_t)(blockIdx.z * 3 + widx) * BSZ * DIM;

    const int srow = tid >> 3;          // 0..31
    const int scol = (tid & 7) * 8;     // 0..56

    const float* aptr  = x + (size_t)(m0 + srow) * DIM + koff + scol;
    const float* bptr0 = W + (size_t)(n0 + srow) * DIM + koff + scol;
    const float* bptr1 = W + (size_t)(n0 + 32 + srow) * DIM + koff + scol;

    f32x4 g[3][2];
    #define LOAD_PASSES(k0)  do {                                   \
        g[0][0] = *(const f32x4*)(aptr  + (k0));                    \
        g[0][1] = *(const f32x4*)(aptr  + (k0) + 4);                \
        g[1][0] = *(const f32x4*)(bptr0 + (k0));                    \
        g[1][1] = *(const f32x4*)(bptr0 + (k0) + 4);                \
        g[2][0] = *(const f32x4*)(bptr1 + (k0));                    \
        g[2][1] = *(const f32x4*)(bptr1 + (k0) + 4);                \
    } while (0)

    LOAD_PASSES(0);

    const f32x4 zero = {0.f, 0.f, 0.f, 0.f};
    f32x4 acc0 = zero, acc1 = zero;
    int buf = 0;

    for (int it = 0; it < 8; ++it) {
        unsigned* ad  = (unsigned*)(As[buf] + srow * 72 + scol);
        ad[0] = pack_bf16x2(g[0][0][0], g[0][0][1]);
        ad[1] = pack_bf16x2(g[0][0][2], g[0][0][3]);
        ad[2] = pack_bf16x2(g[0][1][0], g[0][1][1]);
        ad[3] = pack_bf16x2(g[0][1][2], g[0][1][3]);
        unsigned* bd0 = (unsigned*)(Bs[buf] + srow * 72 + scol);
        bd0[0] = pack_bf16x2(g[1][0][0], g[1][0][1]);
        bd0[1] = pack_bf16x2(g[1][0][2], g[1][0][3]);
        bd0[2] = pack_bf16x2(g[1][1][0], g[1][1][1]);
        bd0[3] = pack_bf16x2(g[1][1][2], g[1][1][3]);
        unsigned* bd1 = (unsigned*)(Bs[buf] + (32 + srow) * 72 + scol);
        bd1[0] = pack_bf16x2(g[2][0][0], g[2][0][1]);
        bd1[1] = pack_bf16x2(g[2][0][2], g[2][0][3]);
        bd1[2] = pack_bf16x2(g[2][1][0], g[2][1][1]);
        bd1[3] = pack_bf16x2(g[2][1][2], g[2][1][3]);
        __syncthreads();

        if (it < 7) { const int k0 = (it + 1) * 64; LOAD_PASSES(k0); }

        #pragma unroll
        for (int kc = 0; kc < 64; kc += 32) {
            short8 a  = *(const short8*)(As[buf] + (16 * wm + l15) * 72 + kc + quad * 8);
            short8 b0 = *(const short8*)(Bs[buf] + (32 * wn +      l15) * 72 + kc + quad * 8);
            short8 b1 = *(const short8*)(Bs[buf] + (32 * wn + 16 + l15) * 72 + kc + quad * 8);
            acc0 = __builtin_amdgcn_mfma_f32_16x16x32_bf16(a, b0, acc0, 0, 0, 0);
            acc1 = __builtin_amdgcn_mfma_f32_16x16x32_bf16(a, b1, acc1, 0, 0, 0);
        }
        buf ^= 1;
    }
    #undef LOAD_PASSES

    // C/D layout: col = lane&15, row = quad*4 + reg
    f32x4 accs[2] = {acc0, acc1};
    #pragma unroll
    for (int nt = 0; nt < 2; ++nt) {
        const int col = n0 + 32 * wn + nt * 16 + l15;
        const float bval = (blockIdx.z == 0) ? bias[col] : 0.f;
        #pragma unroll
        for (int r = 0; r < 4; ++r) {
            const int row = m0 + 16 * wm + quad * 4 + r;
            out[(size_t)row * DIM + col] = accs[nt][r] + bval;
        }
    }
}

// ---------------------------------------------------------------------------
// Kernel 2: rank-1 attention via 1-D function interpolation.
// out[b,j] = gamma * N(q_j)/Z(q_j) + x[b,j], Z(s)=sum_i e^{s k_i},
// N(s)=sum_i e^{s k_i} v_i — smooth scalar functions of s per sample b.
// R9: 64-pt uniform grid over [qmin_b, qmax_b] (was 128; 4-pt Lagrange
// interp rel err ~0.023*(k*h)^4 grows 16x to ~5e-4 on N,Z -> ~1.5e-4 abs
// on out (gamma~0.15), still ~100x under the bf16-GEMM rounding floor).
// Thread t: grid pt g = t&63, i-chunk = t>>6 (16 chunks x 64 i's; k/v LDS
// reads are wave-broadcast). Phase-1 exp/VALU work halves vs R8.
// ---------------------------------------------------------------------------
__global__ __launch_bounds__(1024) void attn_kernel(
    const float* __restrict__ qkv,
    const float* __restrict__ x,
    const float* __restrict__ gamma,
    float* __restrict__ out)
{
    const int b   = blockIdx.x;
    const int tid = threadIdx.x;

    __shared__ __align__(16) float ks[DIM];      // 4 KB
    __shared__ __align__(16) float vs[DIM];      // 4 KB
    __shared__ float redZ[16][64];               // 4 KB
    __shared__ float redN[16][64];               // 4 KB
    __shared__ float gridZ[64], gridN[64];       // 512 B
    __shared__ float wmax[16], wmin[16];

    const size_t S = (size_t)BSZ * DIM;
    const size_t o = (size_t)b * DIM + tid;
    const float qj = qkv[o] + qkv[3 * S + o];          // q = half0 + half1
    const float kt = qkv[S + o] + qkv[4 * S + o];
    const float vt = qkv[2 * S + o] + qkv[5 * S + o];
    ks[tid] = kt;
    vs[tid] = vt;

    // per-b qmin/qmax
    float mx = qj, mn = qj;
    #pragma unroll
    for (int off = 32; off; off >>= 1) {
        mx = fmaxf(mx, __shfl_xor(mx, off));
        mn = fminf(mn, __shfl_xor(mn, off));
    }
    if ((tid & 63) == 0) { wmax[tid >> 6] = mx; wmin[tid >> 6] = mn; }
    __syncthreads();
    float gmx = wmax[0], gmn = wmin[0];
    #pragma unroll
    for (int w = 1; w < 16; ++w) {
        gmx = fmaxf(gmx, wmax[w]);
        gmn = fminf(gmn, wmin[w]);
    }

    const float h     = (gmx - gmn) * (1.0f / 60.0f) + 1e-20f;
    const float inv_h = 1.0f / h;
    const float s0    = gmn;

    // phase 1: Z,N partials on the grid.  s_g = s0 + (g-1)*h, g in [0,64).
    const int g  = tid & 63;
    const int ch = tid >> 6;
    const float m = (s0 + (float)(g - 1) * h) * 1.4426950408889634f;

    const f32x4* k4 = (const f32x4*)(ks + ch * 64);
    const f32x4* v4 = (const f32x4*)(vs + ch * 64);
    f32x4 z4 = {0.f, 0.f, 0.f, 0.f};
    f32x4 n4 = {0.f, 0.f, 0.f, 0.f};
    #pragma unroll 4
    for (int p = 0; p < 16; ++p) {
        const f32x4 kk = k4[p];
        const f32x4 vv = v4[p];
        f32x4 e;
        e[0] = EXP2F(m * kk[0]); e[1] = EXP2F(m * kk[1]);
        e[2] = EXP2F(m * kk[2]); e[3] = EXP2F(m * kk[3]);
        z4 += e;
        n4 = __builtin_elementwise_fma(e, vv, n4);
    }
    redZ[ch][g] = (z4[0] + z4[1]) + (z4[2] + z4[3]);
    redN[ch][g] = (n4[0] + n4[1]) + (n4[2] + n4[3]);
    __syncthreads();

    if (tid < 64) {
        float zs = redZ[0][tid], ns = redN[0][tid];
        #pragma unroll
        for (int c = 1; c < 16; ++c) { zs += redZ[c][tid]; ns += redN[c][tid]; }
        gridZ[tid] = zs;
        gridN[tid] = ns;
    }
    __syncthreads();

    // phase 2: 4-point Lagrange interpolation at u = (q-s0)/h + 1 in [1,61]
    const float u = (qj - s0) * inv_h + 1.0f;
    int g0 = (int)floorf(u);
    g0 = min(max(g0, 1), 61);
    const float t  = u - (float)g0;
    const float a  = t * t - 1.0f;                      // (t-1)(t+1)
    const float Lm1 = t * (t - 1.0f) * (t - 2.0f) * (-1.0f / 6.0f);
    const float L0  = a * (t - 2.0f) * 0.5f;
    const float L1  = t * (t + 1.0f) * (t - 2.0f) * (-0.5f);
    const float L2  = t * a * (1.0f / 6.0f);

    const float Z = Lm1 * gridZ[g0 - 1] + L0 * gridZ[g0] + L1 * gridZ[g0 + 1] + L2 * gridZ[g0 + 2];
    const float N = Lm1 * gridN[g0 - 1] + L0 * gridN[g0] + L1 * gridN[g0 + 1] + L2 * gridN[g0 + 2];

    out[o] = fmaf(gamma[0], N / Z, x[o]);
}

extern "C" void kernel_launch(void* const* d_in, const int* in_sizes, int n_in,
                              void* d_out, int out_size, void* d_ws, size_t ws_size,
                              hipStream_t stream) {
    (void)in_sizes; (void)n_in; (void)out_size; (void)ws_size;
    const float* x     = (const float*)d_in[0];
    const float* Wq    = (const float*)d_in[1];
    const float* bq    = (const float*)d_in[2];
    const float* Wk    = (const float*)d_in[3];
    const float* bk    = (const float*)d_in[4];
    const float* Wv    = (const float*)d_in[5];
    const float* bv    = (const float*)d_in[6];
    const float* gamma = (const float*)d_in[7];

    float* qkv = (float*)d_ws;             // 2 halves x 3 mats x 1 MB = 6 MB
    float* out = (float*)d_out;            // fp32 — reference output dtype

    qkv_gemm<<<dim3(48, 8, 2), 256, 0, stream>>>(x, Wq, bq, Wk, bk, Wv, bv, qkv);
    attn_kernel<<<dim3(BSZ), 1024, 0, stream>>>(qkv, x, gamma, out);
}